// Round 1
// baseline (2510.774 us; speedup 1.0000x reference)
//
#include <hip/hip_runtime.h>
#include <math.h>

// LinearAttention fp32 baseline.
// x:[32,256,64,64] Wqkv:[384,256] bqkv:[384] Wout:[256,128] bout:[256] gamma,beta:[256]
// out:[32,256,64,64]
//
// ws layout (floats):
//   q_ws   @ 0        : 32*128*4096 = 16777216   (softmaxed+scaled q, [b][head*32+d][n])
//   part   @ 16777216 : 2048*4096   = 8388608    (per-block context partials)
//   ctx    @ 25165824 : 32*4096     = 131072     ([b][h][d][e])
//   gstats @ 25296896 : 128                      (gsum[32], gsumsq[32], mean[32], rstd[32])
// total ~101.2 MB

#define NPIX 4096
#define SCALE 0.17677669529663687f

__global__ __launch_bounds__(256) void k1_qkv(
    const float* __restrict__ x, const float* __restrict__ Wqkv,
    const float* __restrict__ bqkv, float* __restrict__ q_ws,
    float* __restrict__ part)
{
    __shared__ float xs[16384];   // [c][p] 256x64; reused as k[4][32][64] | v[4][32][64]
    const int blk  = blockIdx.x;
    const int b    = blk >> 6;
    const int n0   = (blk & 63) << 6;
    const int tid  = threadIdx.x;
    const int lane = tid & 63;
    const int s    = __builtin_amdgcn_readfirstlane(tid >> 6);  // wave-uniform head/section

    // stage x tile (coalesced)
    const float* xb = x + (size_t)b * (256 * NPIX) + n0;
    for (int i = tid; i < 16384; i += 256) {
        int c = i >> 6, p = i & 63;
        xs[i] = xb[(size_t)c * NPIX + p];
    }
    __syncthreads();

    float qa[32], ka[32], va[32];
    #pragma unroll
    for (int d = 0; d < 32; ++d) { qa[d] = 0.f; ka[d] = 0.f; va[d] = 0.f; }

    // W rows for this section: q rows s*32.., k rows 128+s*32.., v rows 256+s*32..
    const float4* Wq4 = (const float4*)(Wqkv + (size_t)s * 8192);
    const float4* Wk4 = (const float4*)(Wqkv + 32768 + (size_t)s * 8192);
    const float4* Wv4 = (const float4*)(Wqkv + 65536 + (size_t)s * 8192);

    for (int cc = 0; cc < 64; ++cc) {
        const float x0 = xs[(4*cc+0)*64 + lane];
        const float x1 = xs[(4*cc+1)*64 + lane];
        const float x2 = xs[(4*cc+2)*64 + lane];
        const float x3 = xs[(4*cc+3)*64 + lane];
        #pragma unroll
        for (int d = 0; d < 32; ++d) {
            float4 wq = Wq4[d*64 + cc];
            qa[d] += x0*wq.x + x1*wq.y + x2*wq.z + x3*wq.w;
            float4 wk = Wk4[d*64 + cc];
            ka[d] += x0*wk.x + x1*wk.y + x2*wk.z + x3*wk.w;
            float4 wv = Wv4[d*64 + cc];
            va[d] += x0*wv.x + x1*wv.y + x2*wv.z + x3*wv.w;
        }
    }

    // bias, softmax(q over d)*SCALE, softmax(k over d), bias(v)
    float qm = -1e30f, km = -1e30f;
    #pragma unroll
    for (int d = 0; d < 32; ++d) {
        qa[d] += bqkv[s*32 + d];
        ka[d] += bqkv[128 + s*32 + d];
        va[d] += bqkv[256 + s*32 + d];
        qm = fmaxf(qm, qa[d]); km = fmaxf(km, ka[d]);
    }
    float qsum = 0.f, ksum = 0.f;
    #pragma unroll
    for (int d = 0; d < 32; ++d) {
        qa[d] = __expf(qa[d] - qm); qsum += qa[d];
        ka[d] = __expf(ka[d] - km); ksum += ka[d];
    }
    const float qr = SCALE / qsum, kr = 1.f / ksum;
    #pragma unroll
    for (int d = 0; d < 32; ++d) { qa[d] *= qr; ka[d] *= kr; }

    // store q for kernel 3 (coalesced over lane)
    float* qdst = q_ws + ((size_t)(b*4 + s) * 32) * NPIX + n0 + lane;
    #pragma unroll
    for (int d = 0; d < 32; ++d) qdst[(size_t)d * NPIX] = qa[d];

    // stage softmaxed k and v into LDS (reuse xs)
    __syncthreads();
    #pragma unroll
    for (int d = 0; d < 32; ++d) {
        xs[(s*32 + d)*64 + lane]        = ka[d];
        xs[8192 + (s*32 + d)*64 + lane] = va[d];
    }
    __syncthreads();

    // per-block partial context for head s: ctx[d][e] = sum_p k[d][p]*v[e][p]
    // thread (s, lane): 4x4 tile, d0=(lane>>3)*4, e0=(lane&7)*4
    const int d0 = (lane >> 3) << 2;
    const int e0 = (lane & 7) << 2;
    float cacc[16];
    #pragma unroll
    for (int t = 0; t < 16; ++t) cacc[t] = 0.f;
    const float* kl = xs + s*2048;
    const float* vl = xs + 8192 + s*2048;
    for (int p = 0; p < 64; ++p) {
        float kd[4], ve[4];
        #pragma unroll
        for (int i = 0; i < 4; ++i) kd[i] = kl[(d0+i)*64 + p];
        #pragma unroll
        for (int j = 0; j < 4; ++j) ve[j] = vl[(e0+j)*64 + p];
        #pragma unroll
        for (int i = 0; i < 4; ++i)
            #pragma unroll
            for (int j = 0; j < 4; ++j)
                cacc[i*4+j] += kd[i]*ve[j];
    }
    float* pdst = part + (size_t)blk * 4096 + s*1024;
    #pragma unroll
    for (int i = 0; i < 4; ++i)
        #pragma unroll
        for (int j = 0; j < 4; ++j)
            pdst[(d0+i)*32 + e0 + j] = cacc[i*4+j];
}

__global__ __launch_bounds__(256) void k2_reduce(
    const float* __restrict__ part, float* __restrict__ ctx)
{
    int i = blockIdx.x * 256 + threadIdx.x;   // < 131072
    int b = i >> 12, r = i & 4095;
    const float* p = part + (size_t)b * 64 * 4096 + r;
    float sum = 0.f;
    #pragma unroll 8
    for (int j = 0; j < 64; ++j) sum += p[(size_t)j * 4096];
    ctx[i] = sum;
}

__global__ __launch_bounds__(256) void k3_out(
    const float* __restrict__ q_ws, const float* __restrict__ ctx,
    const float* __restrict__ Wout, const float* __restrict__ bout,
    float* __restrict__ out, float* __restrict__ gstats)
{
    __shared__ float qs[8192];    // [ch][p] 128x64; attn written back in place
    __shared__ float ctxs[4096];  // [h][d][e]; reused for block reduction
    const int blk  = blockIdx.x;
    const int b    = blk >> 6;
    const int n0   = (blk & 63) << 6;
    const int tid  = threadIdx.x;
    const int lane = tid & 63;
    const int s    = __builtin_amdgcn_readfirstlane(tid >> 6);

    const float* qb = q_ws + (size_t)b * 524288 + n0;
    for (int i = tid; i < 8192; i += 256) {
        int ch = i >> 6, p = i & 63;
        qs[i] = qb[(size_t)ch * NPIX + p];
    }
    for (int i = tid; i < 4096; i += 256) ctxs[i] = ctx[b*4096 + i];
    __syncthreads();

    // attn[s*32+e][lane] = sum_d ctx[s][d][e] * q[s*32+d][lane]
    float aa[32];
    #pragma unroll
    for (int e = 0; e < 32; ++e) aa[e] = 0.f;
    const float4* cr = (const float4*)(ctxs + s*1024);
    for (int d = 0; d < 32; ++d) {
        float qv = qs[(s*32 + d)*64 + lane];
        #pragma unroll
        for (int jj = 0; jj < 8; ++jj) {
            float4 cv = cr[d*8 + jj];
            aa[jj*4+0] += qv*cv.x; aa[jj*4+1] += qv*cv.y;
            aa[jj*4+2] += qv*cv.z; aa[jj*4+3] += qv*cv.w;
        }
    }
    // write attn back into qs: thread owns (rows s*32..s*32+31, column lane) - no race
    #pragma unroll
    for (int e = 0; e < 32; ++e) qs[(s*32 + e)*64 + lane] = aa[e];
    __syncthreads();

    // out2[o][p] = bout[o] + sum_c2 Wout[o][c2]*attn[c2][p], o = s*64+j
    float acc2[64];
    #pragma unroll
    for (int j = 0; j < 64; ++j) acc2[j] = 0.f;
    const float4* W4 = (const float4*)(Wout + (size_t)s * 64 * 128);
    for (int cc = 0; cc < 32; ++cc) {
        const float x0 = qs[(4*cc+0)*64 + lane];
        const float x1 = qs[(4*cc+1)*64 + lane];
        const float x2 = qs[(4*cc+2)*64 + lane];
        const float x3 = qs[(4*cc+3)*64 + lane];
        #pragma unroll
        for (int j = 0; j < 64; ++j) {
            float4 w = W4[j*32 + cc];
            acc2[j] += x0*w.x + x1*w.y + x2*w.z + x3*w.w;
        }
    }
    float ls = 0.f, lss = 0.f;
    float* od = out + ((size_t)b * 256 + s*64) * NPIX + n0 + lane;
    #pragma unroll
    for (int j = 0; j < 64; ++j) {
        float v = acc2[j] + bout[s*64 + j];
        od[(size_t)j * NPIX] = v;
        ls += v; lss += v*v;
    }

    // block reduction of sum / sumsq -> 2 atomics
    __syncthreads();
    ctxs[tid] = ls; ctxs[256 + tid] = lss;
    __syncthreads();
    for (int off = 128; off > 0; off >>= 1) {
        if (tid < off) {
            ctxs[tid]       += ctxs[tid + off];
            ctxs[256 + tid] += ctxs[256 + tid + off];
        }
        __syncthreads();
    }
    if (tid == 0) {
        atomicAdd(&gstats[b],      ctxs[0]);
        atomicAdd(&gstats[32 + b], ctxs[256]);
    }
}

__global__ void k4_stats(float* __restrict__ gstats)
{
    int t = threadIdx.x;
    if (t < 32) {
        const float inv_cnt = 1.0f / 1048576.0f;  // 256*4096
        float m   = gstats[t] * inv_cnt;
        float var = gstats[32 + t] * inv_cnt - m*m;
        gstats[64 + t] = m;
        gstats[96 + t] = rsqrtf(var + 1e-5f);
    }
}

__global__ __launch_bounds__(256) void k5_norm(
    float* __restrict__ out, const float* __restrict__ gstats,
    const float* __restrict__ gamma, const float* __restrict__ beta)
{
    size_t gid  = (size_t)blockIdx.x * 256 + threadIdx.x;   // float4 index
    size_t base = gid * 4;
    int b = (int)(base >> 20);          // / (256*4096)
    int o = (int)((base >> 12) & 255);  // / 4096 % 256
    float m   = gstats[64 + b];
    float inv = gstats[96 + b];
    float a = inv * gamma[o];
    float c = beta[o] - m * a;
    float4 v = ((float4*)out)[gid];
    v.x = v.x * a + c; v.y = v.y * a + c;
    v.z = v.z * a + c; v.w = v.w * a + c;
    ((float4*)out)[gid] = v;
}

extern "C" void kernel_launch(void* const* d_in, const int* in_sizes, int n_in,
                              void* d_out, int out_size, void* d_ws, size_t ws_size,
                              hipStream_t stream) {
    const float* x     = (const float*)d_in[0];
    const float* Wqkv  = (const float*)d_in[1];
    const float* bqkv  = (const float*)d_in[2];
    const float* Wout  = (const float*)d_in[3];
    const float* bout  = (const float*)d_in[4];
    const float* gamma = (const float*)d_in[5];
    const float* beta  = (const float*)d_in[6];
    float* out = (float*)d_out;
    float* ws  = (float*)d_ws;

    float* q_ws   = ws;               // 16777216 floats
    float* part   = ws + 16777216;    // 8388608 floats
    float* ctx    = ws + 25165824;    // 131072 floats
    float* gstats = ws + 25296896;    // 128 floats

    hipMemsetAsync(gstats, 0, 64 * sizeof(float), stream);  // gsum+gsumsq
    k1_qkv  <<<2048,  256, 0, stream>>>(x, Wqkv, bqkv, q_ws, part);
    k2_reduce<<<512,  256, 0, stream>>>(part, ctx);
    k3_out  <<<2048,  256, 0, stream>>>(q_ws, ctx, Wout, bout, out, gstats);
    k4_stats<<<1,      64, 0, stream>>>(gstats);
    k5_norm <<<32768, 256, 0, stream>>>(out, gstats, gamma, beta);
}

// Round 2
// 884.760 us; speedup vs baseline: 2.8378x; 2.8378x over previous
//
#include <hip/hip_runtime.h>
#include <math.h>

// LinearAttention — k1 rewritten as bf16 MFMA (16x16x32), k2/k3/k4/k5 unchanged.
// x:[32,256,64,64] Wqkv:[384,256] bqkv:[384] Wout:[256,128] bout:[256] gamma,beta:[256]
//
// ws layout (floats):
//   q_ws   @ 0        : 32*128*4096 = 16777216   (softmaxed+scaled q, [b][head*32+d][n], fp32)
//   part   @ 16777216 : 2048*4096   = 8388608    (per-block context partials)
//   ctx    @ 25165824 : 32*4096     = 131072     ([b][h][d][e])
//   gstats @ 25296896 : 128

#define NPIX 4096
#define SCALE 0.17677669529663687f

typedef __bf16 bf16;
typedef __bf16 bf16x4 __attribute__((ext_vector_type(4)));
typedef __bf16 bf16x8 __attribute__((ext_vector_type(8)));
typedef float  f32x4  __attribute__((ext_vector_type(4)));

// ---------------------------------------------------------------------------
// k1: per block: batch b, 64-pixel tile. 4 waves, wave s = head s.
// GEMM qkv[384,64] = Wqkv[384,256] x x[256,64] via MFMA, K-chunked (8 x 32).
// LDS: xT [64 px][256 c] bf16, XOR-swizzled groups-of-8  (32768 B)
//      wch [384 rows][40] bf16 chunk of 32 k + pad        (30720 B)  total 63488 B
// overlay phase 2: k_lds[4][32][72] + v_lds[4][32][72] bf16 (36864 B)
// ---------------------------------------------------------------------------
__global__ __launch_bounds__(256) void k1_qkv(
    const float* __restrict__ x, const float* __restrict__ Wqkv,
    const float* __restrict__ bqkv, float* __restrict__ q_ws,
    float* __restrict__ part)
{
    __shared__ __align__(16) bf16 sm[31744];   // 63488 B
    bf16* xT  = sm;            // 16384 bf16
    bf16* wch = sm + 16384;    // 15360 bf16

    const int blk  = blockIdx.x;
    const int b    = blk >> 6;
    const int n0   = (blk & 63) << 6;
    const int tid  = threadIdx.x;
    const int lane = tid & 63;
    const int s    = __builtin_amdgcn_readfirstlane(tid >> 6);
    const int m16  = lane & 15;
    const int quad = lane >> 4;

    // ---- stage xT (transposed, bf16, swizzled): xT[px][c], phys group = (c>>3) ^ (px&7)
    const float* xb = x + (size_t)b * (256 * NPIX) + n0;
    for (int i = tid; i < 4096; i += 256) {
        int px = i & 63;
        int cq = i >> 6;                 // 4-channel group, 0..63
        const float* xp = xb + (size_t)cq * 4 * NPIX + px;
        float v0 = xp[0], v1 = xp[NPIX], v2 = xp[2*NPIX], v3 = xp[3*NPIX];
        int g  = cq >> 1;
        int o  = (cq & 1) * 4;
        int gp = g ^ (px & 7);
        bf16x4 pk = { (bf16)v0, (bf16)v1, (bf16)v2, (bf16)v3 };
        *(bf16x4*)&xT[px*256 + gp*8 + o] = pk;
    }

    // A rows for this wave (head s): q, k, v sections
    const int rbase0 = s*32;
    const int rbase1 = 128 + s*32;
    const int rbase2 = 256 + s*32;

    f32x4 acc[6][4] = {};  // [m-tile][n-tile], m-tiles: q0,q1,k0,k1,v0,v1

    for (int kc = 0; kc < 8; ++kc) {
        __syncthreads();   // protect wch WAR (and xT visibility on kc=0)
        // stage W chunk [384][32] -> wch[384][40]
        for (int i = tid; i < 3072; i += 256) {
            int row = i >> 3, c4 = i & 7;
            float4 w = ((const float4*)Wqkv)[(size_t)row*64 + kc*8 + c4];
            bf16x4 pk = { (bf16)w.x, (bf16)w.y, (bf16)w.z, (bf16)w.w };
            *(bf16x4*)&wch[row*40 + c4*4] = pk;
        }
        __syncthreads();

        // B-frags: x for 4 n-tiles
        bf16x8 bfr[4];
        #pragma unroll
        for (int nt = 0; nt < 4; ++nt) {
            int px = nt*16 + m16;
            int gp = (kc*4 + quad) ^ (px & 7);
            bfr[nt] = *(const bf16x8*)&xT[px*256 + gp*8];
        }
        // A-frags + MFMA
        #pragma unroll
        for (int mt = 0; mt < 6; ++mt) {
            int rb  = (mt < 2) ? rbase0 : (mt < 4) ? rbase1 : rbase2;
            int row = rb + (mt & 1)*16 + m16;
            bf16x8 afr = *(const bf16x8*)&wch[row*40 + quad*8];
            #pragma unroll
            for (int nt = 0; nt < 4; ++nt)
                acc[mt][nt] = __builtin_amdgcn_mfma_f32_16x16x32_bf16(afr, bfr[nt], acc[mt][nt], 0, 0, 0);
        }
    }

    // ---- biases (tiny, L1/L2-hot)
    float bq[8], bk[8], bv[8];
    #pragma unroll
    for (int j = 0; j < 8; ++j) {
        int rr = (j >> 2)*16 + quad*4 + (j & 3);
        bq[j] = bqkv[s*32 + rr];
        bk[j] = bqkv[128 + s*32 + rr];
        bv[j] = bqkv[256 + s*32 + rr];
    }

    // ---- q: bias + softmax over d (cross-quad shuffle) + SCALE, store fp32 to q_ws
    #pragma unroll
    for (int nt = 0; nt < 4; ++nt) {
        float v[8]; float mx = -1e30f;
        #pragma unroll
        for (int j = 0; j < 8; ++j) { v[j] = acc[j>>2][nt][j&3] + bq[j]; mx = fmaxf(mx, v[j]); }
        mx = fmaxf(mx, __shfl_xor(mx, 16));
        mx = fmaxf(mx, __shfl_xor(mx, 32));
        float sum = 0.f;
        #pragma unroll
        for (int j = 0; j < 8; ++j) { v[j] = __expf(v[j] - mx); sum += v[j]; }
        sum += __shfl_xor(sum, 16);
        sum += __shfl_xor(sum, 32);
        float rs = SCALE / sum;
        #pragma unroll
        for (int j = 0; j < 8; ++j) {
            int d = (j>>2)*16 + quad*4 + (j&3);
            q_ws[(size_t)((b*4 + s)*32 + d) * NPIX + n0 + nt*16 + m16] = v[j] * rs;
        }
    }

    // ---- k softmax + v bias -> LDS (overlay region; barrier first)
    __syncthreads();
    bf16* kl = sm + s*2304;          // [32][72]
    bf16* vl = sm + 9216 + s*2304;   // [32][72]
    #pragma unroll
    for (int nt = 0; nt < 4; ++nt) {
        float v[8]; float mx = -1e30f;
        #pragma unroll
        for (int j = 0; j < 8; ++j) { v[j] = acc[2 + (j>>2)][nt][j&3] + bk[j]; mx = fmaxf(mx, v[j]); }
        mx = fmaxf(mx, __shfl_xor(mx, 16));
        mx = fmaxf(mx, __shfl_xor(mx, 32));
        float sum = 0.f;
        #pragma unroll
        for (int j = 0; j < 8; ++j) { v[j] = __expf(v[j] - mx); sum += v[j]; }
        sum += __shfl_xor(sum, 16);
        sum += __shfl_xor(sum, 32);
        float rs = 1.f / sum;
        #pragma unroll
        for (int j = 0; j < 8; ++j) {
            int d  = (j>>2)*16 + quad*4 + (j&3);
            int px = nt*16 + m16;
            kl[d*72 + px] = (bf16)(v[j] * rs);
            vl[d*72 + px] = (bf16)(acc[4 + (j>>2)][nt][j&3] + bv[j]);
        }
    }
    __syncthreads();

    // ---- context partial via MFMA: ctx[d][e] = sum_p k[d][p] * v[e][p]
    f32x4 cacc[2][2] = {};
    #pragma unroll
    for (int ks = 0; ks < 2; ++ks) {
        bf16x8 ak[2], bvv[2];
        #pragma unroll
        for (int mt = 0; mt < 2; ++mt)
            ak[mt] = *(const bf16x8*)&kl[(mt*16 + m16)*72 + ks*32 + quad*8];
        #pragma unroll
        for (int nt = 0; nt < 2; ++nt)
            bvv[nt] = *(const bf16x8*)&vl[(nt*16 + m16)*72 + ks*32 + quad*8];
        #pragma unroll
        for (int mt = 0; mt < 2; ++mt)
            #pragma unroll
            for (int nt = 0; nt < 2; ++nt)
                cacc[mt][nt] = __builtin_amdgcn_mfma_f32_16x16x32_bf16(ak[mt], bvv[nt], cacc[mt][nt], 0, 0, 0);
    }
    float* pdst = part + (size_t)blk * 4096 + s*1024;
    #pragma unroll
    for (int mt = 0; mt < 2; ++mt)
        #pragma unroll
        for (int nt = 0; nt < 2; ++nt)
            #pragma unroll
            for (int r = 0; r < 4; ++r)
                pdst[(mt*16 + quad*4 + r)*32 + nt*16 + m16] = cacc[mt][nt][r];
}

// ---------------------------------------------------------------------------
__global__ __launch_bounds__(256) void k2_reduce(
    const float* __restrict__ part, float* __restrict__ ctx)
{
    int i = blockIdx.x * 256 + threadIdx.x;   // < 131072
    int b = i >> 12, r = i & 4095;
    const float* p = part + (size_t)b * 64 * 4096 + r;
    float sum = 0.f;
    #pragma unroll 8
    for (int j = 0; j < 64; ++j) sum += p[(size_t)j * 4096];
    ctx[i] = sum;
}

__global__ __launch_bounds__(256) void k3_out(
    const float* __restrict__ q_ws, const float* __restrict__ ctx,
    const float* __restrict__ Wout, const float* __restrict__ bout,
    float* __restrict__ out, float* __restrict__ gstats)
{
    __shared__ float qs[8192];    // [ch][p] 128x64; attn written back in place
    __shared__ float ctxs[4096];  // [h][d][e]; reused for block reduction
    const int blk  = blockIdx.x;
    const int b    = blk >> 6;
    const int n0   = (blk & 63) << 6;
    const int tid  = threadIdx.x;
    const int lane = tid & 63;
    const int s    = __builtin_amdgcn_readfirstlane(tid >> 6);

    const float* qb = q_ws + (size_t)b * 524288 + n0;
    for (int i = tid; i < 8192; i += 256) {
        int ch = i >> 6, p = i & 63;
        qs[i] = qb[(size_t)ch * NPIX + p];
    }
    for (int i = tid; i < 4096; i += 256) ctxs[i] = ctx[b*4096 + i];
    __syncthreads();

    // attn[s*32+e][lane] = sum_d ctx[s][d][e] * q[s*32+d][lane]
    float aa[32];
    #pragma unroll
    for (int e = 0; e < 32; ++e) aa[e] = 0.f;
    const float4* cr = (const float4*)(ctxs + s*1024);
    for (int d = 0; d < 32; ++d) {
        float qv = qs[(s*32 + d)*64 + lane];
        #pragma unroll
        for (int jj = 0; jj < 8; ++jj) {
            float4 cv = cr[d*8 + jj];
            aa[jj*4+0] += qv*cv.x; aa[jj*4+1] += qv*cv.y;
            aa[jj*4+2] += qv*cv.z; aa[jj*4+3] += qv*cv.w;
        }
    }
    #pragma unroll
    for (int e = 0; e < 32; ++e) qs[(s*32 + e)*64 + lane] = aa[e];
    __syncthreads();

    float acc2[64];
    #pragma unroll
    for (int j = 0; j < 64; ++j) acc2[j] = 0.f;
    const float4* W4 = (const float4*)(Wout + (size_t)s * 64 * 128);
    for (int cc = 0; cc < 32; ++cc) {
        const float x0 = qs[(4*cc+0)*64 + lane];
        const float x1 = qs[(4*cc+1)*64 + lane];
        const float x2 = qs[(4*cc+2)*64 + lane];
        const float x3 = qs[(4*cc+3)*64 + lane];
        #pragma unroll
        for (int j = 0; j < 64; ++j) {
            float4 w = W4[j*32 + cc];
            acc2[j] += x0*w.x + x1*w.y + x2*w.z + x3*w.w;
        }
    }
    float ls = 0.f, lss = 0.f;
    float* od = out + ((size_t)b * 256 + s*64) * NPIX + n0 + lane;
    #pragma unroll
    for (int j = 0; j < 64; ++j) {
        float v = acc2[j] + bout[s*64 + j];
        od[(size_t)j * NPIX] = v;
        ls += v; lss += v*v;
    }

    __syncthreads();
    ctxs[tid] = ls; ctxs[256 + tid] = lss;
    __syncthreads();
    for (int off = 128; off > 0; off >>= 1) {
        if (tid < off) {
            ctxs[tid]       += ctxs[tid + off];
            ctxs[256 + tid] += ctxs[256 + tid + off];
        }
        __syncthreads();
    }
    if (tid == 0) {
        atomicAdd(&gstats[b],      ctxs[0]);
        atomicAdd(&gstats[32 + b], ctxs[256]);
    }
}

__global__ void k4_stats(float* __restrict__ gstats)
{
    int t = threadIdx.x;
    if (t < 32) {
        const float inv_cnt = 1.0f / 1048576.0f;  // 256*4096
        float m   = gstats[t] * inv_cnt;
        float var = gstats[32 + t] * inv_cnt - m*m;
        gstats[64 + t] = m;
        gstats[96 + t] = rsqrtf(var + 1e-5f);
    }
}

__global__ __launch_bounds__(256) void k5_norm(
    float* __restrict__ out, const float* __restrict__ gstats,
    const float* __restrict__ gamma, const float* __restrict__ beta)
{
    size_t gid  = (size_t)blockIdx.x * 256 + threadIdx.x;
    size_t base = gid * 4;
    int b = (int)(base >> 20);
    int o = (int)((base >> 12) & 255);
    float m   = gstats[64 + b];
    float inv = gstats[96 + b];
    float a = inv * gamma[o];
    float c = beta[o] - m * a;
    float4 v = ((float4*)out)[gid];
    v.x = v.x * a + c; v.y = v.y * a + c;
    v.z = v.z * a + c; v.w = v.w * a + c;
    ((float4*)out)[gid] = v;
}

extern "C" void kernel_launch(void* const* d_in, const int* in_sizes, int n_in,
                              void* d_out, int out_size, void* d_ws, size_t ws_size,
                              hipStream_t stream) {
    const float* x     = (const float*)d_in[0];
    const float* Wqkv  = (const float*)d_in[1];
    const float* bqkv  = (const float*)d_in[2];
    const float* Wout  = (const float*)d_in[3];
    const float* bout  = (const float*)d_in[4];
    const float* gamma = (const float*)d_in[5];
    const float* beta  = (const float*)d_in[6];
    float* out = (float*)d_out;
    float* ws  = (float*)d_ws;

    float* q_ws   = ws;
    float* part   = ws + 16777216;
    float* ctx    = ws + 25165824;
    float* gstats = ws + 25296896;

    hipMemsetAsync(gstats, 0, 64 * sizeof(float), stream);
    k1_qkv  <<<2048,  256, 0, stream>>>(x, Wqkv, bqkv, q_ws, part);
    k2_reduce<<<512,  256, 0, stream>>>(part, ctx);
    k3_out  <<<2048,  256, 0, stream>>>(q_ws, ctx, Wout, bout, out, gstats);
    k4_stats<<<1,      64, 0, stream>>>(gstats);
    k5_norm <<<32768, 256, 0, stream>>>(out, gstats, gamma, beta);
}

// Round 3
// 395.500 us; speedup vs baseline: 6.3484x; 2.2371x over previous
//
#include <hip/hip_runtime.h>
#include <math.h>

// LinearAttention — all GEMMs bf16 MFMA 16x16x32, fragment loads direct from
// global where layout permits (coalesced 64B lines via 4 quads x 16B).
//
// ws layout (float units):
//   q_wsT   @ 0         : bf16[32*4096*128]  [b][px][ch] softmaxed*SCALE q   (8388608 f)
//   wqkv_bf @ 8388608   : bf16[384*256]      row-major                      (49152 f)
//   wout_bf @ 8437760   : bf16[256*128]      row-major                      (16384 f)
//   ctxT_bf @ 8454144   : bf16[32*4*32*32]   [b][h][e][d] (transposed)      (65536 f)
//   part    @ 16777216  : f32 [2048][4096]   per-block context partials     (8388608 f)
//   gstats  @ 25165824  : f32 [128]

#define NPIX 4096
#define SCALE 0.17677669529663687f

typedef __bf16 bf16;
typedef __bf16 bf16x4 __attribute__((ext_vector_type(4)));
typedef __bf16 bf16x8 __attribute__((ext_vector_type(8)));
typedef float  f32x4  __attribute__((ext_vector_type(4)));

// ---------------------------------------------------------------------------
__global__ __launch_bounds__(256) void k0_convert(
    const float* __restrict__ Wqkv, const float* __restrict__ Wout,
    bf16* __restrict__ wqkv_bf, bf16* __restrict__ wout_bf)
{
    int i = blockIdx.x * 256 + threadIdx.x;   // < 131072
    if (i < 98304) wqkv_bf[i] = (bf16)Wqkv[i];
    else           wout_bf[i - 98304] = (bf16)Wout[i - 98304];
}

// ---------------------------------------------------------------------------
// k1: block = (batch b, 64-px tile). 4 waves, wave s = head s.
// qkv[384,64] = Wqkv x x. A-frags direct from global bf16 Wqkv (L2-hot).
// B-frags from LDS xT (transposed, XOR-swizzled). Barrier-free K-loop.
// LDS: xT 16384 bf16 (32 KB); overlay phase2: k/v [4][32][72]*2 = 36864 B.
// ---------------------------------------------------------------------------
__global__ __launch_bounds__(256) void k1_qkv(
    const float* __restrict__ x, const bf16* __restrict__ wqkv_bf,
    const float* __restrict__ bqkv, bf16* __restrict__ q_wsT,
    float* __restrict__ part)
{
    __shared__ __align__(16) bf16 sm[18432];   // 36864 B
    bf16* xT = sm;   // 16384 bf16 [px][256ch], group(8) swizzle gp = g ^ (px&7)

    const int blk  = blockIdx.x;
    const int b    = blk >> 6;
    const int n0   = (blk & 63) << 6;
    const int tid  = threadIdx.x;
    const int lane = tid & 63;
    const int s    = __builtin_amdgcn_readfirstlane(tid >> 6);
    const int m16  = lane & 15;
    const int quad = lane >> 4;

    // stage xT (transposed, bf16, swizzled)
    const float* xb = x + (size_t)b * (256 * NPIX) + n0;
    for (int i = tid; i < 4096; i += 256) {
        int px = i & 63;
        int cq = i >> 6;
        const float* xp = xb + (size_t)cq * 4 * NPIX + px;
        float v0 = xp[0], v1 = xp[NPIX], v2 = xp[2*NPIX], v3 = xp[3*NPIX];
        int g  = cq >> 1;
        int o  = (cq & 1) * 4;
        int gp = g ^ (px & 7);
        bf16x4 pk = { (bf16)v0, (bf16)v1, (bf16)v2, (bf16)v3 };
        *(bf16x4*)&xT[px*256 + gp*8 + o] = pk;
    }
    __syncthreads();

    f32x4 acc[6][4] = {};   // m-tiles: q0,q1,k0,k1,v0,v1 ; 4 n-tiles

    for (int kc = 0; kc < 8; ++kc) {
        bf16x8 bfr[4];
        #pragma unroll
        for (int nt = 0; nt < 4; ++nt) {
            int px = nt*16 + m16;
            int gp = (kc*4 + quad) ^ (px & 7);
            bfr[nt] = *(const bf16x8*)&xT[px*256 + gp*8];
        }
        #pragma unroll
        for (int mt = 0; mt < 6; ++mt) {
            int row = (mt >> 1)*128 + s*32 + (mt & 1)*16 + m16;
            bf16x8 afr = *(const bf16x8*)&wqkv_bf[(size_t)row*256 + kc*32 + quad*8];
            #pragma unroll
            for (int nt = 0; nt < 4; ++nt)
                acc[mt][nt] = __builtin_amdgcn_mfma_f32_16x16x32_bf16(afr, bfr[nt], acc[mt][nt], 0, 0, 0);
        }
    }

    // biases
    float bq[8], bk[8], bv[8];
    #pragma unroll
    for (int j = 0; j < 8; ++j) {
        int rr = (j >> 2)*16 + quad*4 + (j & 3);
        bq[j] = bqkv[s*32 + rr];
        bk[j] = bqkv[128 + s*32 + rr];
        bv[j] = bqkv[256 + s*32 + rr];
    }

    // q: softmax over d + SCALE -> q_wsT[b][px][ch] bf16 (L2 merges 8B stores)
    #pragma unroll
    for (int nt = 0; nt < 4; ++nt) {
        float v[8]; float mx = -1e30f;
        #pragma unroll
        for (int j = 0; j < 8; ++j) { v[j] = acc[j>>2][nt][j&3] + bq[j]; mx = fmaxf(mx, v[j]); }
        mx = fmaxf(mx, __shfl_xor(mx, 16));
        mx = fmaxf(mx, __shfl_xor(mx, 32));
        float sum = 0.f;
        #pragma unroll
        for (int j = 0; j < 8; ++j) { v[j] = __expf(v[j] - mx); sum += v[j]; }
        sum += __shfl_xor(sum, 16);
        sum += __shfl_xor(sum, 32);
        float rs = SCALE / sum;
        size_t rowb = (size_t)(b*4096 + n0 + nt*16 + m16) * 128;
        #pragma unroll
        for (int mt = 0; mt < 2; ++mt) {
            bf16x4 pk = { (bf16)(v[mt*4+0]*rs), (bf16)(v[mt*4+1]*rs),
                          (bf16)(v[mt*4+2]*rs), (bf16)(v[mt*4+3]*rs) };
            *(bf16x4*)&q_wsT[rowb + s*32 + mt*16 + quad*4] = pk;
        }
    }

    // k softmax + v bias -> LDS overlay (xT dead; barrier for WAR)
    __syncthreads();
    bf16* kl = sm + s*2304;          // [32][72]
    bf16* vl = sm + 9216 + s*2304;   // [32][72]
    #pragma unroll
    for (int nt = 0; nt < 4; ++nt) {
        float v[8]; float mx = -1e30f;
        #pragma unroll
        for (int j = 0; j < 8; ++j) { v[j] = acc[2 + (j>>2)][nt][j&3] + bk[j]; mx = fmaxf(mx, v[j]); }
        mx = fmaxf(mx, __shfl_xor(mx, 16));
        mx = fmaxf(mx, __shfl_xor(mx, 32));
        float sum = 0.f;
        #pragma unroll
        for (int j = 0; j < 8; ++j) { v[j] = __expf(v[j] - mx); sum += v[j]; }
        sum += __shfl_xor(sum, 16);
        sum += __shfl_xor(sum, 32);
        float rs = 1.f / sum;
        #pragma unroll
        for (int j = 0; j < 8; ++j) {
            int d  = (j>>2)*16 + quad*4 + (j&3);
            int px = nt*16 + m16;
            kl[d*72 + px] = (bf16)(v[j] * rs);
            vl[d*72 + px] = (bf16)(acc[4 + (j>>2)][nt][j&3] + bv[j]);
        }
    }
    __syncthreads();

    // context partial: ctx[d][e] = sum_p k[d][p]*v[e][p]
    f32x4 cacc[2][2] = {};
    #pragma unroll
    for (int ks = 0; ks < 2; ++ks) {
        bf16x8 ak[2], bvv[2];
        #pragma unroll
        for (int mt = 0; mt < 2; ++mt)
            ak[mt] = *(const bf16x8*)&kl[(mt*16 + m16)*72 + ks*32 + quad*8];
        #pragma unroll
        for (int nt = 0; nt < 2; ++nt)
            bvv[nt] = *(const bf16x8*)&vl[(nt*16 + m16)*72 + ks*32 + quad*8];
        #pragma unroll
        for (int mt = 0; mt < 2; ++mt)
            #pragma unroll
            for (int nt = 0; nt < 2; ++nt)
                cacc[mt][nt] = __builtin_amdgcn_mfma_f32_16x16x32_bf16(ak[mt], bvv[nt], cacc[mt][nt], 0, 0, 0);
    }
    float* pdst = part + (size_t)blk * 4096 + s*1024;
    #pragma unroll
    for (int mt = 0; mt < 2; ++mt)
        #pragma unroll
        for (int nt = 0; nt < 2; ++nt)
            #pragma unroll
            for (int r = 0; r < 4; ++r)
                pdst[(mt*16 + quad*4 + r)*32 + nt*16 + m16] = cacc[mt][nt][r];
}

// ---------------------------------------------------------------------------
__global__ __launch_bounds__(256) void k2_reduce(
    const float* __restrict__ part, bf16* __restrict__ ctxT_bf)
{
    int i = blockIdx.x * 256 + threadIdx.x;   // < 131072
    int b = i >> 12, r = i & 4095;
    const float* p = part + (size_t)b * 64 * 4096 + r;
    float sum = 0.f;
    #pragma unroll 8
    for (int j = 0; j < 64; ++j) sum += p[(size_t)j * 4096];
    int h = r >> 10, d = (r >> 5) & 31, e = r & 31;
    ctxT_bf[(size_t)((b*4 + h)*32 + e)*32 + d] = (bf16)sum;   // transposed
}

// ---------------------------------------------------------------------------
// k3: block = (b, 64-px tile). Wave s: attn for head s, then out rows s*64..+63.
// attn[e][p] = ctxT x qT  (frags direct from global, 8 MFMAs)
// out = Wout x attn       (A direct from global bf16 Wout; B from LDS attnT)
// LDS: attnT [64][128] bf16 XOR-swizzled (16 KB) + red[512] f32.
// ---------------------------------------------------------------------------
__global__ __launch_bounds__(256) void k3_out(
    const bf16* __restrict__ q_wsT, const bf16* __restrict__ ctxT_bf,
    const bf16* __restrict__ wout_bf, const float* __restrict__ bout,
    float* __restrict__ out, float* __restrict__ gstats)
{
    __shared__ __align__(16) bf16 attnT[8192];
    __shared__ float red[512];
    const int blk  = blockIdx.x;
    const int b    = blk >> 6;
    const int n0   = (blk & 63) << 6;
    const int tid  = threadIdx.x;
    const int lane = tid & 63;
    const int s    = __builtin_amdgcn_readfirstlane(tid >> 6);
    const int m16  = lane & 15;
    const int quad = lane >> 4;

    // ---- attn GEMM (head s): A = ctxT[b][s][e][d], B^T = q_wsT[b][px][s*32+d]
    f32x4 aacc[2][4] = {};
    {
        bf16x8 afr[2], bfr[4];
        const bf16* ctxs = ctxT_bf + (size_t)(b*4 + s) * 1024;
        #pragma unroll
        for (int mt = 0; mt < 2; ++mt)
            afr[mt] = *(const bf16x8*)&ctxs[(mt*16 + m16)*32 + quad*8];
        const bf16* qb = q_wsT + (size_t)(b*4096 + n0) * 128 + s*32;
        #pragma unroll
        for (int nt = 0; nt < 4; ++nt)
            bfr[nt] = *(const bf16x8*)&qb[(size_t)(nt*16 + m16)*128 + quad*8];
        #pragma unroll
        for (int mt = 0; mt < 2; ++mt)
            #pragma unroll
            for (int nt = 0; nt < 4; ++nt)
                aacc[mt][nt] = __builtin_amdgcn_mfma_f32_16x16x32_bf16(afr[mt], bfr[nt], aacc[mt][nt], 0, 0, 0);
    }

    // write attnT[p][ch] swizzled: gp = (ch>>3) ^ (p&15)
    #pragma unroll
    for (int mt = 0; mt < 2; ++mt)
        #pragma unroll
        for (int nt = 0; nt < 4; ++nt) {
            int p   = nt*16 + m16;
            int chb = s*32 + mt*16 + quad*4;
            int gp  = (chb >> 3) ^ m16;
            bf16x4 pk = { (bf16)aacc[mt][nt][0], (bf16)aacc[mt][nt][1],
                          (bf16)aacc[mt][nt][2], (bf16)aacc[mt][nt][3] };
            *(bf16x4*)&attnT[p*128 + gp*8 + (quad & 1)*4] = pk;
        }
    __syncthreads();

    // ---- Wout GEMM: rows o = s*64 + mt*16 + m16, K = 128 (4 chunks)
    f32x4 acc[4][4] = {};
    const bf16* wb = wout_bf + (size_t)s * 64 * 128;
    for (int kc = 0; kc < 4; ++kc) {
        bf16x8 wfr[4], xfr[4];
        #pragma unroll
        for (int mt = 0; mt < 4; ++mt)
            wfr[mt] = *(const bf16x8*)&wb[(size_t)(mt*16 + m16)*128 + kc*32 + quad*8];
        #pragma unroll
        for (int nt = 0; nt < 4; ++nt) {
            int p  = nt*16 + m16;
            int gp = (kc*4 + quad) ^ m16;
            xfr[nt] = *(const bf16x8*)&attnT[p*128 + gp*8];
        }
        #pragma unroll
        for (int mt = 0; mt < 4; ++mt)
            #pragma unroll
            for (int nt = 0; nt < 4; ++nt)
                acc[mt][nt] = __builtin_amdgcn_mfma_f32_16x16x32_bf16(wfr[mt], xfr[nt], acc[mt][nt], 0, 0, 0);
    }

    // epilogue: bias, coalesced f32 stores, per-lane stats
    float ls = 0.f, lss = 0.f;
    float* ob = out + ((size_t)b*256 + s*64) * NPIX + n0;
    #pragma unroll
    for (int mt = 0; mt < 4; ++mt) {
        #pragma unroll
        for (int r = 0; r < 4; ++r) {
            int o = mt*16 + quad*4 + r;
            float bo = bout[s*64 + o];
            #pragma unroll
            for (int nt = 0; nt < 4; ++nt) {
                float v = acc[mt][nt][r] + bo;
                ob[(size_t)o*NPIX + nt*16 + m16] = v;
                ls += v; lss += v*v;
            }
        }
    }

    red[tid] = ls; red[256 + tid] = lss;
    __syncthreads();
    for (int off = 128; off > 0; off >>= 1) {
        if (tid < off) {
            red[tid]       += red[tid + off];
            red[256 + tid] += red[256 + tid + off];
        }
        __syncthreads();
    }
    if (tid == 0) {
        atomicAdd(&gstats[b],      red[0]);
        atomicAdd(&gstats[32 + b], red[256]);
    }
}

// ---------------------------------------------------------------------------
__global__ void k4_stats(float* __restrict__ gstats)
{
    int t = threadIdx.x;
    if (t < 32) {
        const float inv_cnt = 1.0f / 1048576.0f;   // 256*4096
        float m   = gstats[t] * inv_cnt;
        float var = gstats[32 + t] * inv_cnt - m*m;
        gstats[64 + t] = m;
        gstats[96 + t] = rsqrtf(var + 1e-5f);
    }
}

__global__ __launch_bounds__(256) void k5_norm(
    float* __restrict__ out, const float* __restrict__ gstats,
    const float* __restrict__ gamma, const float* __restrict__ beta)
{
    size_t gid  = (size_t)blockIdx.x * 256 + threadIdx.x;
    size_t base = gid * 4;
    int b = (int)(base >> 20);
    int o = (int)((base >> 12) & 255);
    float m   = gstats[64 + b];
    float inv = gstats[96 + b];
    float a = inv * gamma[o];
    float c = beta[o] - m * a;
    float4 v = ((float4*)out)[gid];
    v.x = v.x * a + c; v.y = v.y * a + c;
    v.z = v.z * a + c; v.w = v.w * a + c;
    ((float4*)out)[gid] = v;
}

extern "C" void kernel_launch(void* const* d_in, const int* in_sizes, int n_in,
                              void* d_out, int out_size, void* d_ws, size_t ws_size,
                              hipStream_t stream) {
    const float* x     = (const float*)d_in[0];
    const float* Wqkv  = (const float*)d_in[1];
    const float* bqkv  = (const float*)d_in[2];
    const float* Wout  = (const float*)d_in[3];
    const float* bout  = (const float*)d_in[4];
    const float* gamma = (const float*)d_in[5];
    const float* beta  = (const float*)d_in[6];
    float* out = (float*)d_out;
    float* ws  = (float*)d_ws;

    bf16*  q_wsT   = (bf16*)ws;
    bf16*  wqkv_bf = (bf16*)(ws + 8388608);
    bf16*  wout_bf = (bf16*)(ws + 8437760);
    bf16*  ctxT_bf = (bf16*)(ws + 8454144);
    float* part    = ws + 16777216;
    float* gstats  = ws + 25165824;

    hipMemsetAsync(gstats, 0, 64 * sizeof(float), stream);
    k0_convert<<<512,  256, 0, stream>>>(Wqkv, Wout, wqkv_bf, wout_bf);
    k1_qkv    <<<2048, 256, 0, stream>>>(x, wqkv_bf, bqkv, q_wsT, part);
    k2_reduce <<<512,  256, 0, stream>>>(part, ctxT_bf);
    k3_out    <<<2048, 256, 0, stream>>>(q_wsT, ctxT_bf, wout_bf, bout, out, gstats);
    k4_stats  <<<1,     64, 0, stream>>>(gstats);
    k5_norm   <<<32768,256, 0, stream>>>(out, gstats, gamma, beta);
}